// Round 17
// baseline (40.806 us; speedup 1.0000x reference)
//
#include <hip/hip_runtime.h>
#include <math.h>

// Problem constants: B=16, N=128, h=256, goal_dim=64, obs_dim=128, local=64, skills=16
// R17 = R16 with attn at 512 blocks x 512 threads (4-row tiles, 2 blocks/CU):
// two independent blocks per CU overlap each other's barrier/load stalls.

typedef float f32x4 __attribute__((ext_vector_type(4)));
typedef short s16x8 __attribute__((ext_vector_type(8)));

// ---- workspace layout (float offsets) ----
#define WOBF_OFF  0        // bf16 [256][256] (row-major, = original Wo layout)
#define QBF_OFF   32768    // bf16 [2048][256] row-major
#define KBF_OFF   294912   // bf16 [2048][256] row-major
#define VTBF_OFF  557056   // bf16 [16][256][128]  (V transposed per batch)

// ---- output layout (float offsets, tuple return order) ----
#define LOGIT_OFF 0        // [16][128][16]
#define MASK_OFF  32768    // [16][128][128]
#define ATTN_OFF  294912   // [16][128][128]
#define OUT_OFF   557056   // [16][128][256]

static __device__ __forceinline__ unsigned short f2bf(float x) {
  unsigned int u = __float_as_uint(x);
  u = (u + 0x7fffu + ((u >> 16) & 1u)) >> 16;   // RNE
  return (unsigned short)u;
}
static __device__ __forceinline__ float bf2f(unsigned short h) {
  return __uint_as_float(((unsigned int)h) << 16);
}

// split 8 consecutive f32 (16B-aligned) into hi/lo bf16 MFMA fragments
static __device__ __forceinline__ void split8(const float* __restrict__ p,
                                              s16x8* hi, s16x8* lo) {
  float4 x0 = *(const float4*)p;
  float4 x1 = *(const float4*)(p + 4);
  float xs[8] = {x0.x, x0.y, x0.z, x0.w, x1.x, x1.y, x1.z, x1.w};
#pragma unroll
  for (int j = 0; j < 8; j++) {
    unsigned short h = f2bf(xs[j]);
    (*hi)[j] = (short)h;
    (*lo)[j] = (short)f2bf(xs[j] - bf2f(h));
  }
}
#define MFMA(a, b, c) __builtin_amdgcn_mfma_f32_16x16x32_bf16((a), (b), (c), 0, 0, 0)

// ---------------- proj_k: R10/R16 verbatim (XCD-aligned mapping) -------------
__global__ __launch_bounds__(512) void proj_k(
    const float* __restrict__ goals, const float* __restrict__ agents,
    const float* __restrict__ Wq, const float* __restrict__ bq,
    const float* __restrict__ Wk, const float* __restrict__ bk,
    const float* __restrict__ Wv, const float* __restrict__ bv,
    const float* __restrict__ Wo, float* __restrict__ ws) {
  unsigned short* qbf  = (unsigned short*)(ws + QBF_OFF);
  unsigned short* kbf  = (unsigned short*)(ws + KBF_OFF);
  unsigned short* vtbf = (unsigned short*)(ws + VTBF_OFF);
  unsigned short* wobf = (unsigned short*)(ws + WOBF_OFF);

  __shared__ __align__(16) float xg[16 * 68];
  __shared__ __align__(16) float xa[16 * 132];

  int t = threadIdx.x;
  int bid = blockIdx.x;
  int xcd = bid & 7, j = bid >> 3;
  int bb = 2 * xcd + (j & 1);
  int sub = j >> 1;
  int r0 = bb * 128 + (sub >> 1) * 16;
  int colbase = (sub & 1) * 128;

  for (int i = t; i < 1024; i += 512) xg[(i >> 6) * 68 + (i & 63)] = goals[(size_t)r0 * 64 + i];
  for (int i = t; i < 2048; i += 512) xa[(i >> 7) * 132 + (i & 127)] = agents[(size_t)r0 * 128 + i];
  if (t < 256) {
    int jj = bid * 256 + t;
    wobf[jj] = f2bf(Wo[jj]);
  }
  __syncthreads();

  int w = t >> 6, l = t & 63, lr = l & 15, lc = l >> 4;
  int oc = colbase + w * 16 + lr;

  {
    f32x4 acc = {0.f, 0.f, 0.f, 0.f};
#pragma unroll
    for (int kk = 0; kk < 2; kk++) {
      s16x8 ahi, alo, bhi, blo;
      split8(&xg[lr * 68 + kk * 32 + lc * 8], &ahi, &alo);
      split8(&Wq[(size_t)oc * 64 + kk * 32 + lc * 8], &bhi, &blo);
      acc = MFMA(ahi, bhi, acc);
      acc = MFMA(alo, bhi, acc);
      acc = MFMA(ahi, blo, acc);
    }
    float bqv = bq[oc];
#pragma unroll
    for (int q = 0; q < 4; q++)
      qbf[(size_t)(r0 + 4 * lc + q) * 256 + oc] = f2bf(acc[q] + bqv);
  }
  {
    f32x4 acc = {0.f, 0.f, 0.f, 0.f};
#pragma unroll
    for (int kk = 0; kk < 4; kk++) {
      s16x8 ahi, alo, bhi, blo;
      split8(&xa[lr * 132 + kk * 32 + lc * 8], &ahi, &alo);
      split8(&Wk[(size_t)oc * 128 + kk * 32 + lc * 8], &bhi, &blo);
      acc = MFMA(ahi, bhi, acc);
      acc = MFMA(alo, bhi, acc);
      acc = MFMA(ahi, blo, acc);
    }
    float bkv = bk[oc];
#pragma unroll
    for (int q = 0; q < 4; q++)
      kbf[(size_t)(r0 + 4 * lc + q) * 256 + oc] = f2bf(acc[q] + bkv);
  }
  {
    f32x4 acc = {0.f, 0.f, 0.f, 0.f};
#pragma unroll
    for (int kk = 0; kk < 4; kk++) {
      s16x8 ahi, alo, bhi, blo;
      split8(&xa[lr * 132 + kk * 32 + lc * 8], &ahi, &alo);
      split8(&Wv[(size_t)oc * 128 + kk * 32 + lc * 8], &bhi, &blo);
      acc = MFMA(ahi, bhi, acc);
      acc = MFMA(alo, bhi, acc);
      acc = MFMA(ahi, blo, acc);
    }
    float bvv = bv[oc];
    int m0 = r0 & 127;
#pragma unroll
    for (int q = 0; q < 4; q++)
      vtbf[(size_t)(bb * 256 + oc) * 128 + m0 + 4 * lc + q] = f2bf(acc[q] + bvv);
  }
}

// ---------------- attn_k: 512 blocks x 512 thr, 4-row tiles, 2 blocks/CU ----
// xcd = bid&7, idx = bid>>3 (0..63); b = 2*xcd + (idx&1); n0 = (idx>>1)*4.
__global__ __launch_bounds__(512, 4) void attn_k(
    const float* __restrict__ goals, const float* __restrict__ agents_local,
    const float* __restrict__ u1, const float* __restrict__ u2,
    const float* __restrict__ bo, const float* __restrict__ Wsm,
    const float* __restrict__ bs, const float* __restrict__ ws,
    float* __restrict__ out) {
  const unsigned short* Qbf  = (const unsigned short*)(ws + QBF_OFF);
  const unsigned short* Kbf  = (const unsigned short*)(ws + KBF_OFF);
  const unsigned short* VTbf = (const unsigned short*)(ws + VTBF_OFF);
  const unsigned short* Wobf = (const unsigned short*)(ws + WOBF_OFF);
  float* o_logit = out + LOGIT_OFF;
  float* o_mask  = out + MASK_OFF;
  float* o_attn  = out + ATTN_OFF;
  float* o_out   = out + OUT_OFF;

  int bid = blockIdx.x;
  int xcd = bid & 7, idx = bid >> 3;
  int b  = 2 * xcd + (idx & 1);
  int n0 = (idx >> 1) << 2;            // 0..124 step 4
  int rtile = n0 & 0x70;               // 16-row MFMA window base
  int soff  = n0 & 12;                 // our 4 rows within the window
  int t = threadIdx.x;
  int w = t >> 6, l = t & 63, lr = l & 15, lc = l >> 4;

  __shared__ __align__(16) float Sp[4][132];             // our 4 logit rows
  __shared__ __align__(16) unsigned short Wb[16 * 136];  // attn*mask (A of PV)
  __shared__ __align__(16) unsigned short Ib[16 * 264];  // info bf16 (A of O)
  __shared__ __align__(16) float outb[4 * 260];          // out rows (skill in)
  __shared__ float redmax[4][2], redsum[4][2];

  // ---- prefetch: u1/u2 (NT), bo x2, 8 VT B-frags (hidden under L+S) ----
  int pm = t & 127, prl = t >> 7;      // row prl (0..3), col pm
  int prow = b * 128 + n0 + prl;
  float uu1 = __builtin_nontemporal_load(&u1[(size_t)prow * 128 + pm]);
  float uu2 = __builtin_nontemporal_load(&u2[(size_t)prow * 128 + pm]);
  float bov0 = bo[w * 16 + lr];
  float bov1 = bo[(w + 8) * 16 + lr];
  const s16x8* vtp0 = (const s16x8*)(VTbf + (size_t)(b * 256 + w * 16 + lr) * 128);
  const s16x8* vtp1 = (const s16x8*)(VTbf + (size_t)(b * 256 + (w + 8) * 16 + lr) * 128);
  s16x8 fv0 = vtp0[lc], fv1 = vtp0[4 + lc], fv2 = vtp0[8 + lc], fv3 = vtp0[12 + lc];
  s16x8 fw0 = vtp1[lc], fw1 = vtp1[4 + lc], fw2 = vtp1[8 + lc], fw3 = vtp1[12 + lc];

  // ---- phase L: logits MFMA. wave w -> m-tile w, k=256 (8 MFMAs) ----
  {
    const s16x8* ap = (const s16x8*)(Qbf + (size_t)(b * 128 + rtile + lr) * 256);
    const s16x8* bp = (const s16x8*)(Kbf + (size_t)(b * 128 + w * 16 + lr) * 256);
    f32x4 acc = {0.f, 0.f, 0.f, 0.f};
#pragma unroll
    for (int kk = 0; kk < 8; kk++)
      acc = MFMA(ap[kk * 4 + lc], bp[kk * 4 + lc], acc);
    if (lc == (soff >> 2)) {           // rows we own (4*lc+q = soff+q)
#pragma unroll
      for (int q = 0; q < 4; q++) Sp[q][w * 16 + lr] = acc[q] * 0.0625f;
    }
    // zero ALL Wb rows (ours rewritten in phase S after the barrier)
    for (int i = t; i < 1088; i += 512) ((unsigned int*)Wb)[i] = 0u;
  }
  __syncthreads();

  // ---- phase S: gumbel-sigmoid mask + scores + softmax (1 pair/thread) ----
  {
    int half = (t >> 6) & 1;
    float lg = Sp[prl][pm];
    float g1 = -__logf(-__logf(uu1 + 1e-20f) + 1e-20f);
    float g2 = -__logf(-__logf(uu2 + 1e-20f) + 1e-20f);
    float mkv = 1.0f / (1.0f + __expf(-(lg + g1 - g2)));   // TAU = 1
    __builtin_nontemporal_store(mkv, &o_mask[(size_t)prow * 128 + pm]);
    float sc = lg + __logf(mkv + 1e-8f);
    float v = sc;
#pragma unroll
    for (int off = 32; off >= 1; off >>= 1) v = fmaxf(v, __shfl_xor(v, off));
    if (l == 0) redmax[prl][half] = v;
    __syncthreads();
    float rmax = fmaxf(redmax[prl][0], redmax[prl][1]);
    float e = __expf(sc - rmax);
    float s = e;
#pragma unroll
    for (int off = 32; off >= 1; off >>= 1) s += __shfl_xor(s, off);
    if (l == 0) redsum[prl][half] = s;
    __syncthreads();
    float rsum = redsum[prl][0] + redsum[prl][1];
    float attn = e / rsum;
    __builtin_nontemporal_store(attn, &o_attn[(size_t)prow * 128 + pm]);
    Wb[(soff + prl) * 136 + pm] = f2bf(attn * mkv);
  }
  __syncthreads();

  // ---- phase PV: info = W x V. wave w -> h-tiles w*16, (w+8)*16 ----
  {
    s16x8 a0 = *(const s16x8*)(Wb + lr * 136 + 0 * 32 + lc * 8);
    s16x8 a1 = *(const s16x8*)(Wb + lr * 136 + 1 * 32 + lc * 8);
    s16x8 a2 = *(const s16x8*)(Wb + lr * 136 + 2 * 32 + lc * 8);
    s16x8 a3 = *(const s16x8*)(Wb + lr * 136 + 3 * 32 + lc * 8);
    f32x4 acc0 = {0.f, 0.f, 0.f, 0.f};
    acc0 = MFMA(a0, fv0, acc0);
    acc0 = MFMA(a1, fv1, acc0);
    acc0 = MFMA(a2, fv2, acc0);
    acc0 = MFMA(a3, fv3, acc0);
    f32x4 acc1 = {0.f, 0.f, 0.f, 0.f};
    acc1 = MFMA(a0, fw0, acc1);
    acc1 = MFMA(a1, fw1, acc1);
    acc1 = MFMA(a2, fw2, acc1);
    acc1 = MFMA(a3, fw3, acc1);
#pragma unroll
    for (int q = 0; q < 4; q++) {
      Ib[(4 * lc + q) * 264 + w * 16 + lr] = f2bf(acc0[q]);
      Ib[(4 * lc + q) * 264 + (w + 8) * 16 + lr] = f2bf(acc1[q]);
    }
  }
  __syncthreads();

  // ---- phase O: out = info x Wo^T. wave w -> g-tiles w*16, (w+8)*16 ----
  {
#pragma unroll
    for (int gs = 0; gs < 2; gs++) {
      int g0 = (w + 8 * gs) * 16;
      f32x4 acc = {0.f, 0.f, 0.f, 0.f};
#pragma unroll
      for (int kk = 0; kk < 8; kk++) {
        s16x8 a = *(const s16x8*)(Ib + lr * 264 + kk * 32 + lc * 8);
        s16x8 bfr = *(const s16x8*)(Wobf + (size_t)(g0 + lr) * 256 + kk * 32 + lc * 8);
        acc = MFMA(a, bfr, acc);
      }
      float bov = gs ? bov1 : bov0;
      if (lc == (soff >> 2)) {         // rows we own: q = 0..3 -> rloc q
#pragma unroll
        for (int q = 0; q < 4; q++) {
          float val = acc[q] + bov;
          __builtin_nontemporal_store(val, &o_out[(size_t)(b * 128 + n0 + q) * 256 + g0 + lr]);
          outb[q * 260 + g0 + lr] = val;
        }
      }
    }
  }
  __syncthreads();

  // ---- phase K: skill logits. t = (rloc<<7)|(s<<3)|p, 8-way split-K ----
  {
    int rloc = t >> 7, s = (t >> 3) & 15, p = t & 7;
    int row = b * 128 + n0 + rloc;
    const float4* Ws4 = (const float4*)(Wsm + s * 384);
    const float4* lp4 = (const float4*)(agents_local + (size_t)row * 64);
    const float4* gp4 = (const float4*)(goals + (size_t)row * 64);
    float acc = 0.f;
#pragma unroll
    for (int i = 0; i < 12; i++) {
      int cc = p * 48 + i * 4;
      float4 c4;
      if (cc < 64)       c4 = lp4[cc >> 2];
      else if (cc < 128) c4 = gp4[(cc - 64) >> 2];
      else               c4 = *(const float4*)&outb[rloc * 260 + (cc - 128)];
      float4 w4 = Ws4[cc >> 2];
      acc = fmaf(w4.x, c4.x, fmaf(w4.y, c4.y, fmaf(w4.z, c4.z, fmaf(w4.w, c4.w, acc))));
    }
    acc += __shfl_xor(acc, 1);
    acc += __shfl_xor(acc, 2);
    acc += __shfl_xor(acc, 4);
    if (p == 0) __builtin_nontemporal_store(acc + bs[s], &o_logit[row * 16 + s]);
  }
}

extern "C" void kernel_launch(void* const* d_in, const int* in_sizes, int n_in,
                              void* d_out, int out_size, void* d_ws, size_t ws_size,
                              hipStream_t stream) {
  const float* goals        = (const float*)d_in[0];
  const float* agents       = (const float*)d_in[1];
  const float* agents_local = (const float*)d_in[2];
  const float* u1           = (const float*)d_in[3];
  const float* u2           = (const float*)d_in[4];
  const float* Wq = (const float*)d_in[5];
  const float* bq = (const float*)d_in[6];
  const float* Wk = (const float*)d_in[7];
  const float* bk = (const float*)d_in[8];
  const float* Wv = (const float*)d_in[9];
  const float* bv = (const float*)d_in[10];
  const float* Wo = (const float*)d_in[11];
  const float* bo = (const float*)d_in[12];
  const float* Wsm = (const float*)d_in[13];
  const float* bs  = (const float*)d_in[14];
  float* out = (float*)d_out;
  float* ws  = (float*)d_ws;

  proj_k<<<256, 512, 0, stream>>>(goals, agents, Wq, bq, Wk, bk, Wv, bv, Wo, ws);
  attn_k<<<512, 512, 0, stream>>>(goals, agents_local, u1, u2, bo, Wsm, bs, ws, out);
}

// Round 18
// 33.947 us; speedup vs baseline: 1.2021x; 1.2021x over previous
//
#include <hip/hip_runtime.h>
#include <math.h>

// Problem constants: B=16, N=128, h=256, goal_dim=64, obs_dim=128, local=64, skills=16
// R18 = R16 (best, 33.83us) + coalesced output write-back through LDS:
// mask/attn staged in LDS, emitted as float4 NT bursts during phase PV;
// o_out emitted as float4 from outb during phase SK (was 64B scatter).

typedef float f32x4 __attribute__((ext_vector_type(4)));
typedef short s16x8 __attribute__((ext_vector_type(8)));

// ---- workspace layout (float offsets) ----
#define WOBF_OFF  0        // bf16 [256][256] (row-major, = original Wo layout)
#define QBF_OFF   32768    // bf16 [2048][256] row-major
#define KBF_OFF   294912   // bf16 [2048][256] row-major
#define VTBF_OFF  557056   // bf16 [16][256][128]  (V transposed per batch)

// ---- output layout (float offsets, tuple return order) ----
#define LOGIT_OFF 0        // [16][128][16]
#define MASK_OFF  32768    // [16][128][128]
#define ATTN_OFF  294912   // [16][128][128]
#define OUT_OFF   557056   // [16][128][256]

static __device__ __forceinline__ unsigned short f2bf(float x) {
  unsigned int u = __float_as_uint(x);
  u = (u + 0x7fffu + ((u >> 16) & 1u)) >> 16;   // RNE
  return (unsigned short)u;
}
static __device__ __forceinline__ float bf2f(unsigned short h) {
  return __uint_as_float(((unsigned int)h) << 16);
}

// split 8 consecutive f32 (16B-aligned) into hi/lo bf16 MFMA fragments
static __device__ __forceinline__ void split8(const float* __restrict__ p,
                                              s16x8* hi, s16x8* lo) {
  float4 x0 = *(const float4*)p;
  float4 x1 = *(const float4*)(p + 4);
  float xs[8] = {x0.x, x0.y, x0.z, x0.w, x1.x, x1.y, x1.z, x1.w};
#pragma unroll
  for (int j = 0; j < 8; j++) {
    unsigned short h = f2bf(xs[j]);
    (*hi)[j] = (short)h;
    (*lo)[j] = (short)f2bf(xs[j] - bf2f(h));
  }
}
#define MFMA(a, b, c) __builtin_amdgcn_mfma_f32_16x16x32_bf16((a), (b), (c), 0, 0, 0)

// ---------------- proj_k: R10/R16 verbatim (XCD-aligned mapping) -------------
__global__ __launch_bounds__(512) void proj_k(
    const float* __restrict__ goals, const float* __restrict__ agents,
    const float* __restrict__ Wq, const float* __restrict__ bq,
    const float* __restrict__ Wk, const float* __restrict__ bk,
    const float* __restrict__ Wv, const float* __restrict__ bv,
    const float* __restrict__ Wo, float* __restrict__ ws) {
  unsigned short* qbf  = (unsigned short*)(ws + QBF_OFF);
  unsigned short* kbf  = (unsigned short*)(ws + KBF_OFF);
  unsigned short* vtbf = (unsigned short*)(ws + VTBF_OFF);
  unsigned short* wobf = (unsigned short*)(ws + WOBF_OFF);

  __shared__ __align__(16) float xg[16 * 68];
  __shared__ __align__(16) float xa[16 * 132];

  int t = threadIdx.x;
  int bid = blockIdx.x;
  int xcd = bid & 7, j = bid >> 3;
  int bb = 2 * xcd + (j & 1);
  int sub = j >> 1;
  int r0 = bb * 128 + (sub >> 1) * 16;
  int colbase = (sub & 1) * 128;

  for (int i = t; i < 1024; i += 512) xg[(i >> 6) * 68 + (i & 63)] = goals[(size_t)r0 * 64 + i];
  for (int i = t; i < 2048; i += 512) xa[(i >> 7) * 132 + (i & 127)] = agents[(size_t)r0 * 128 + i];
  if (t < 256) {
    int jj = bid * 256 + t;
    wobf[jj] = f2bf(Wo[jj]);
  }
  __syncthreads();

  int w = t >> 6, l = t & 63, lr = l & 15, lc = l >> 4;
  int oc = colbase + w * 16 + lr;

  {
    f32x4 acc = {0.f, 0.f, 0.f, 0.f};
#pragma unroll
    for (int kk = 0; kk < 2; kk++) {
      s16x8 ahi, alo, bhi, blo;
      split8(&xg[lr * 68 + kk * 32 + lc * 8], &ahi, &alo);
      split8(&Wq[(size_t)oc * 64 + kk * 32 + lc * 8], &bhi, &blo);
      acc = MFMA(ahi, bhi, acc);
      acc = MFMA(alo, bhi, acc);
      acc = MFMA(ahi, blo, acc);
    }
    float bqv = bq[oc];
#pragma unroll
    for (int q = 0; q < 4; q++)
      qbf[(size_t)(r0 + 4 * lc + q) * 256 + oc] = f2bf(acc[q] + bqv);
  }
  {
    f32x4 acc = {0.f, 0.f, 0.f, 0.f};
#pragma unroll
    for (int kk = 0; kk < 4; kk++) {
      s16x8 ahi, alo, bhi, blo;
      split8(&xa[lr * 132 + kk * 32 + lc * 8], &ahi, &alo);
      split8(&Wk[(size_t)oc * 128 + kk * 32 + lc * 8], &bhi, &blo);
      acc = MFMA(ahi, bhi, acc);
      acc = MFMA(alo, bhi, acc);
      acc = MFMA(ahi, blo, acc);
    }
    float bkv = bk[oc];
#pragma unroll
    for (int q = 0; q < 4; q++)
      kbf[(size_t)(r0 + 4 * lc + q) * 256 + oc] = f2bf(acc[q] + bkv);
  }
  {
    f32x4 acc = {0.f, 0.f, 0.f, 0.f};
#pragma unroll
    for (int kk = 0; kk < 4; kk++) {
      s16x8 ahi, alo, bhi, blo;
      split8(&xa[lr * 132 + kk * 32 + lc * 8], &ahi, &alo);
      split8(&Wv[(size_t)oc * 128 + kk * 32 + lc * 8], &bhi, &blo);
      acc = MFMA(ahi, bhi, acc);
      acc = MFMA(alo, bhi, acc);
      acc = MFMA(ahi, blo, acc);
    }
    float bvv = bv[oc];
    int m0 = r0 & 127;
#pragma unroll
    for (int q = 0; q < 4; q++)
      vtbf[(size_t)(bb * 256 + oc) * 128 + m0 + 4 * lc + q] = f2bf(acc[q] + bvv);
  }
}

// ---------------- attn_k: R16 + coalesced LDS write-back ----------------
__global__ __launch_bounds__(1024) void attn_k(
    const float* __restrict__ goals, const float* __restrict__ agents_local,
    const float* __restrict__ u1, const float* __restrict__ u2,
    const float* __restrict__ bo, const float* __restrict__ Wsm,
    const float* __restrict__ bs, const float* __restrict__ ws,
    float* __restrict__ out) {
  const unsigned short* Qbf  = (const unsigned short*)(ws + QBF_OFF);
  const unsigned short* Kbf  = (const unsigned short*)(ws + KBF_OFF);
  const unsigned short* VTbf = (const unsigned short*)(ws + VTBF_OFF);
  const unsigned short* Wobf = (const unsigned short*)(ws + WOBF_OFF);
  float* o_logit = out + LOGIT_OFF;
  float* o_mask  = out + MASK_OFF;
  float* o_attn  = out + ATTN_OFF;
  float* o_out   = out + OUT_OFF;

  int bid = blockIdx.x;
  int xcd = bid & 7, idx = bid >> 3;
  int b  = 2 * xcd + (idx & 1);
  int n0 = (idx >> 1) << 3;
  int rtile = n0 & 0x70;
  int soff  = n0 & 8;
  int t = threadIdx.x;
  int w = t >> 6, l = t & 63, lr = l & 15, lc = l >> 4;

  __shared__ __align__(16) float Spp[2][8][132];
  __shared__ __align__(16) unsigned short Wb[16 * 136];
  __shared__ __align__(16) unsigned short Ib[16 * 264];
  __shared__ __align__(16) float outb[8 * 260];
  __shared__ __align__(16) float maskb[8 * 128];
  __shared__ __align__(16) float attnb[8 * 128];
  __shared__ float redmax[8][2], redsum[8][2];

  // ---- prefetch: u1/u2 (NT), bo, 4 VT B-frags (hidden under phases L+S) ----
  int pm = t & 127, prl = t >> 7;
  int prow = b * 128 + n0 + prl;
  float uu1 = __builtin_nontemporal_load(&u1[(size_t)prow * 128 + pm]);
  float uu2 = __builtin_nontemporal_load(&u2[(size_t)prow * 128 + pm]);
  int h0g = w * 16;
  float bov = bo[h0g + lr];
  const s16x8* vtp = (const s16x8*)(VTbf + (size_t)(b * 256 + h0g + lr) * 128);
  s16x8 fv0 = vtp[lc], fv1 = vtp[4 + lc], fv2 = vtp[8 + lc], fv3 = vtp[12 + lc];

  // ---- phase L: logits MFMA. wave w: m-tile = w&7, k-half = w>>3 ----
  {
    int mt = w & 7, kh = w >> 3;
    const s16x8* ap = (const s16x8*)(Qbf + (size_t)(b * 128 + rtile + lr) * 256 + kh * 128);
    const s16x8* bp = (const s16x8*)(Kbf + (size_t)(b * 128 + mt * 16 + lr) * 256 + kh * 128);
    f32x4 acc = {0.f, 0.f, 0.f, 0.f};
#pragma unroll
    for (int kk = 0; kk < 4; kk++)
      acc = MFMA(ap[kk * 4 + lc], bp[kk * 4 + lc], acc);
    if ((lc >> 1) == (soff >> 3)) {
#pragma unroll
      for (int q = 0; q < 4; q++) Spp[kh][(4 * lc + q) & 7][mt * 16 + lr] = acc[q];
    }
    if (t < 544) ((unsigned int*)(Wb + (soff ^ 8) * 136))[t] = 0u;
  }
  __syncthreads();

  // ---- phase S: gumbel-sigmoid mask + scores + softmax (LDS staging) ----
  {
    int half = (t >> 6) & 1;
    float lg = (Spp[0][prl][pm] + Spp[1][prl][pm]) * 0.0625f;
    float g1 = -__logf(-__logf(uu1 + 1e-20f) + 1e-20f);
    float g2 = -__logf(-__logf(uu2 + 1e-20f) + 1e-20f);
    float mkv = 1.0f / (1.0f + __expf(-(lg + g1 - g2)));   // TAU = 1
    maskb[prl * 128 + pm] = mkv;
    float sc = lg + __logf(mkv + 1e-8f);
    float v = sc;
#pragma unroll
    for (int off = 32; off >= 1; off >>= 1) v = fmaxf(v, __shfl_xor(v, off));
    if (l == 0) redmax[prl][half] = v;
    __syncthreads();
    float rmax = fmaxf(redmax[prl][0], redmax[prl][1]);
    float e = __expf(sc - rmax);
    float s = e;
#pragma unroll
    for (int off = 32; off >= 1; off >>= 1) s += __shfl_xor(s, off);
    if (l == 0) redsum[prl][half] = s;
    __syncthreads();
    float rsum = redsum[prl][0] + redsum[prl][1];
    float attn = e / rsum;
    attnb[prl * 128 + pm] = attn;
    Wb[(soff + prl) * 136 + pm] = f2bf(attn * mkv);
  }
  __syncthreads();

  // ---- phase PV: mask/attn coalesced write-back + info = W x V ----
  {
    // write-back: 256 float4 mask + 256 float4 attn (1KB/wave NT bursts)
    if (t < 256) {
      int row = t >> 5, c4 = t & 31;
      f32x4 v = *(const f32x4*)&maskb[row * 128 + c4 * 4];
      __builtin_nontemporal_store(v, (f32x4*)&o_mask[(size_t)(b * 128 + n0 + row) * 128 + c4 * 4]);
    } else if (t < 512) {
      int i = t - 256;
      int row = i >> 5, c4 = i & 31;
      f32x4 v = *(const f32x4*)&attnb[row * 128 + c4 * 4];
      __builtin_nontemporal_store(v, (f32x4*)&o_attn[(size_t)(b * 128 + n0 + row) * 128 + c4 * 4]);
    }
    s16x8 a0 = *(const s16x8*)(Wb + lr * 136 + 0 * 32 + lc * 8);
    s16x8 a1 = *(const s16x8*)(Wb + lr * 136 + 1 * 32 + lc * 8);
    s16x8 a2 = *(const s16x8*)(Wb + lr * 136 + 2 * 32 + lc * 8);
    s16x8 a3 = *(const s16x8*)(Wb + lr * 136 + 3 * 32 + lc * 8);
    f32x4 acc = {0.f, 0.f, 0.f, 0.f};
    acc = MFMA(a0, fv0, acc);
    acc = MFMA(a1, fv1, acc);
    acc = MFMA(a2, fv2, acc);
    acc = MFMA(a3, fv3, acc);
#pragma unroll
    for (int q = 0; q < 4; q++) Ib[(4 * lc + q) * 264 + h0g + lr] = f2bf(acc[q]);
  }
  __syncthreads();

  // ---- phase O: out = info x Wo^T -> outb only (global via SK write-back) ---
  {
    int g0 = w * 16;
    f32x4 acc = {0.f, 0.f, 0.f, 0.f};
#pragma unroll
    for (int kk = 0; kk < 8; kk++) {
      s16x8 a = *(const s16x8*)(Ib + lr * 264 + kk * 32 + lc * 8);
      s16x8 bfr = *(const s16x8*)(Wobf + (size_t)(g0 + lr) * 256 + kk * 32 + lc * 8);
      acc = MFMA(a, bfr, acc);
    }
    if ((lc >> 1) == (soff >> 3)) {
#pragma unroll
      for (int q = 0; q < 4; q++) {
        int rloc = (4 * lc + q) & 7;
        outb[rloc * 260 + g0 + lr] = acc[q] + bov;
      }
    }
  }
  __syncthreads();

  // ---- phase SK: o_out coalesced write-back + skill logits ----
  {
    if (t < 512) {
      int row = t >> 6, c4 = t & 63;
      f32x4 v = *(const f32x4*)&outb[row * 260 + c4 * 4];
      __builtin_nontemporal_store(v, (f32x4*)&o_out[(size_t)(b * 128 + n0 + row) * 256 + c4 * 4]);
    }
    int rloc = t >> 7, s = (t >> 3) & 15, p = t & 7;
    int row = b * 128 + n0 + rloc;
    const float4* Ws4 = (const float4*)(Wsm + s * 384);
    const float4* lp4 = (const float4*)(agents_local + (size_t)row * 64);
    const float4* gp4 = (const float4*)(goals + (size_t)row * 64);
    float acc = 0.f;
#pragma unroll
    for (int i = 0; i < 12; i++) {
      int cc = p * 48 + i * 4;
      float4 c4;
      if (cc < 64)       c4 = lp4[cc >> 2];
      else if (cc < 128) c4 = gp4[(cc - 64) >> 2];
      else               c4 = *(const float4*)&outb[rloc * 260 + (cc - 128)];
      float4 w4 = Ws4[cc >> 2];
      acc = fmaf(w4.x, c4.x, fmaf(w4.y, c4.y, fmaf(w4.z, c4.z, fmaf(w4.w, c4.w, acc))));
    }
    acc += __shfl_xor(acc, 1);
    acc += __shfl_xor(acc, 2);
    acc += __shfl_xor(acc, 4);
    if (p == 0) __builtin_nontemporal_store(acc + bs[s], &o_logit[row * 16 + s]);
  }
}

extern "C" void kernel_launch(void* const* d_in, const int* in_sizes, int n_in,
                              void* d_out, int out_size, void* d_ws, size_t ws_size,
                              hipStream_t stream) {
  const float* goals        = (const float*)d_in[0];
  const float* agents       = (const float*)d_in[1];
  const float* agents_local = (const float*)d_in[2];
  const float* u1           = (const float*)d_in[3];
  const float* u2           = (const float*)d_in[4];
  const float* Wq = (const float*)d_in[5];
  const float* bq = (const float*)d_in[6];
  const float* Wk = (const float*)d_in[7];
  const float* bk = (const float*)d_in[8];
  const float* Wv = (const float*)d_in[9];
  const float* bv = (const float*)d_in[10];
  const float* Wo = (const float*)d_in[11];
  const float* bo = (const float*)d_in[12];
  const float* Wsm = (const float*)d_in[13];
  const float* bs  = (const float*)d_in[14];
  float* out = (float*)d_out;
  float* ws  = (float*)d_ws;

  proj_k<<<256, 512, 0, stream>>>(goals, agents, Wq, bq, Wk, bk, Wv, bv, Wo, ws);
  attn_k<<<256, 1024, 0, stream>>>(goals, agents_local, u1, u2, bo, Wsm, bs, ws, out);
}

// Round 19
// 27.934 us; speedup vs baseline: 1.4608x; 1.2152x over previous
//
#include <hip/hip_runtime.h>
#include <math.h>

// Problem constants: B=16, N=128, h=256, goal_dim=64, obs_dim=128, local=64, skills=16
// R19 = R16 (best, 33.83us) + SK-input LDS staging issued BEFORE phase L:
// Wsm (24KB) + agents_local||goals rows (4KB) -> LDS at kernel start, so the
// phase-SK latency tail (loads after the last barrier) disappears.

typedef float f32x4 __attribute__((ext_vector_type(4)));
typedef short s16x8 __attribute__((ext_vector_type(8)));

// ---- workspace layout (float offsets) ----
#define WOBF_OFF  0        // bf16 [256][256] (row-major, = original Wo layout)
#define QBF_OFF   32768    // bf16 [2048][256] row-major
#define KBF_OFF   294912   // bf16 [2048][256] row-major
#define VTBF_OFF  557056   // bf16 [16][256][128]  (V transposed per batch)

// ---- output layout (float offsets, tuple return order) ----
#define LOGIT_OFF 0        // [16][128][16]
#define MASK_OFF  32768    // [16][128][128]
#define ATTN_OFF  294912   // [16][128][128]
#define OUT_OFF   557056   // [16][128][256]

static __device__ __forceinline__ unsigned short f2bf(float x) {
  unsigned int u = __float_as_uint(x);
  u = (u + 0x7fffu + ((u >> 16) & 1u)) >> 16;   // RNE
  return (unsigned short)u;
}
static __device__ __forceinline__ float bf2f(unsigned short h) {
  return __uint_as_float(((unsigned int)h) << 16);
}

// split 8 consecutive f32 (16B-aligned) into hi/lo bf16 MFMA fragments
static __device__ __forceinline__ void split8(const float* __restrict__ p,
                                              s16x8* hi, s16x8* lo) {
  float4 x0 = *(const float4*)p;
  float4 x1 = *(const float4*)(p + 4);
  float xs[8] = {x0.x, x0.y, x0.z, x0.w, x1.x, x1.y, x1.z, x1.w};
#pragma unroll
  for (int j = 0; j < 8; j++) {
    unsigned short h = f2bf(xs[j]);
    (*hi)[j] = (short)h;
    (*lo)[j] = (short)f2bf(xs[j] - bf2f(h));
  }
}
#define MFMA(a, b, c) __builtin_amdgcn_mfma_f32_16x16x32_bf16((a), (b), (c), 0, 0, 0)

// ---------------- proj_k: R10/R16 verbatim (XCD-aligned mapping) -------------
__global__ __launch_bounds__(512) void proj_k(
    const float* __restrict__ goals, const float* __restrict__ agents,
    const float* __restrict__ Wq, const float* __restrict__ bq,
    const float* __restrict__ Wk, const float* __restrict__ bk,
    const float* __restrict__ Wv, const float* __restrict__ bv,
    const float* __restrict__ Wo, float* __restrict__ ws) {
  unsigned short* qbf  = (unsigned short*)(ws + QBF_OFF);
  unsigned short* kbf  = (unsigned short*)(ws + KBF_OFF);
  unsigned short* vtbf = (unsigned short*)(ws + VTBF_OFF);
  unsigned short* wobf = (unsigned short*)(ws + WOBF_OFF);

  __shared__ __align__(16) float xg[16 * 68];
  __shared__ __align__(16) float xa[16 * 132];

  int t = threadIdx.x;
  int bid = blockIdx.x;
  int xcd = bid & 7, j = bid >> 3;
  int bb = 2 * xcd + (j & 1);
  int sub = j >> 1;
  int r0 = bb * 128 + (sub >> 1) * 16;
  int colbase = (sub & 1) * 128;

  for (int i = t; i < 1024; i += 512) xg[(i >> 6) * 68 + (i & 63)] = goals[(size_t)r0 * 64 + i];
  for (int i = t; i < 2048; i += 512) xa[(i >> 7) * 132 + (i & 127)] = agents[(size_t)r0 * 128 + i];
  if (t < 256) {
    int jj = bid * 256 + t;
    wobf[jj] = f2bf(Wo[jj]);
  }
  __syncthreads();

  int w = t >> 6, l = t & 63, lr = l & 15, lc = l >> 4;
  int oc = colbase + w * 16 + lr;

  {
    f32x4 acc = {0.f, 0.f, 0.f, 0.f};
#pragma unroll
    for (int kk = 0; kk < 2; kk++) {
      s16x8 ahi, alo, bhi, blo;
      split8(&xg[lr * 68 + kk * 32 + lc * 8], &ahi, &alo);
      split8(&Wq[(size_t)oc * 64 + kk * 32 + lc * 8], &bhi, &blo);
      acc = MFMA(ahi, bhi, acc);
      acc = MFMA(alo, bhi, acc);
      acc = MFMA(ahi, blo, acc);
    }
    float bqv = bq[oc];
#pragma unroll
    for (int q = 0; q < 4; q++)
      qbf[(size_t)(r0 + 4 * lc + q) * 256 + oc] = f2bf(acc[q] + bqv);
  }
  {
    f32x4 acc = {0.f, 0.f, 0.f, 0.f};
#pragma unroll
    for (int kk = 0; kk < 4; kk++) {
      s16x8 ahi, alo, bhi, blo;
      split8(&xa[lr * 132 + kk * 32 + lc * 8], &ahi, &alo);
      split8(&Wk[(size_t)oc * 128 + kk * 32 + lc * 8], &bhi, &blo);
      acc = MFMA(ahi, bhi, acc);
      acc = MFMA(alo, bhi, acc);
      acc = MFMA(ahi, blo, acc);
    }
    float bkv = bk[oc];
#pragma unroll
    for (int q = 0; q < 4; q++)
      kbf[(size_t)(r0 + 4 * lc + q) * 256 + oc] = f2bf(acc[q] + bkv);
  }
  {
    f32x4 acc = {0.f, 0.f, 0.f, 0.f};
#pragma unroll
    for (int kk = 0; kk < 4; kk++) {
      s16x8 ahi, alo, bhi, blo;
      split8(&xa[lr * 132 + kk * 32 + lc * 8], &ahi, &alo);
      split8(&Wv[(size_t)oc * 128 + kk * 32 + lc * 8], &bhi, &blo);
      acc = MFMA(ahi, bhi, acc);
      acc = MFMA(alo, bhi, acc);
      acc = MFMA(ahi, blo, acc);
    }
    float bvv = bv[oc];
    int m0 = r0 & 127;
#pragma unroll
    for (int q = 0; q < 4; q++)
      vtbf[(size_t)(bb * 256 + oc) * 128 + m0 + 4 * lc + q] = f2bf(acc[q] + bvv);
  }
}

// ---------------- attn_k: R16 + SK-input LDS staging at kernel start --------
__global__ __launch_bounds__(1024) void attn_k(
    const float* __restrict__ goals, const float* __restrict__ agents_local,
    const float* __restrict__ u1, const float* __restrict__ u2,
    const float* __restrict__ bo, const float* __restrict__ Wsm,
    const float* __restrict__ bs, const float* __restrict__ ws,
    float* __restrict__ out) {
  const unsigned short* Qbf  = (const unsigned short*)(ws + QBF_OFF);
  const unsigned short* Kbf  = (const unsigned short*)(ws + KBF_OFF);
  const unsigned short* VTbf = (const unsigned short*)(ws + VTBF_OFF);
  const unsigned short* Wobf = (const unsigned short*)(ws + WOBF_OFF);
  float* o_logit = out + LOGIT_OFF;
  float* o_mask  = out + MASK_OFF;
  float* o_attn  = out + ATTN_OFF;
  float* o_out   = out + OUT_OFF;

  int bid = blockIdx.x;
  int xcd = bid & 7, idx = bid >> 3;
  int b  = 2 * xcd + (idx & 1);
  int n0 = (idx >> 1) << 3;
  int rtile = n0 & 0x70;
  int soff  = n0 & 8;
  int t = threadIdx.x;
  int w = t >> 6, l = t & 63, lr = l & 15, lc = l >> 4;

  __shared__ __align__(16) float Spp[2][8][132];
  __shared__ __align__(16) unsigned short Wb[16 * 136];
  __shared__ __align__(16) unsigned short Ib[16 * 264];
  __shared__ __align__(16) float outb[8 * 260];
  __shared__ __align__(16) float Wsb[16 * 384];   // Wsm staged (24 KB)
  __shared__ __align__(16) float cgb[8 * 128];    // agents_local||goals rows (4 KB)
  __shared__ float redmax[8][2], redsum[8][2];

  // ---- SK-input staging (issued FIRST: latency hides under phases L..O) ----
#pragma unroll
  for (int i = 0; i < 6; i++) Wsb[t + i * 1024] = Wsm[t + i * 1024];
  {
    int r = t >> 7, c = t & 127;
    int row = b * 128 + n0 + r;
    cgb[r * 128 + c] = (c < 64) ? agents_local[(size_t)row * 64 + c]
                                : goals[(size_t)row * 64 + (c - 64)];
  }

  // ---- prefetch: u1/u2 (NT), bo, 4 VT B-frags (hidden under phases L+S) ----
  int pm = t & 127, prl = t >> 7;
  int prow = b * 128 + n0 + prl;
  float uu1 = __builtin_nontemporal_load(&u1[(size_t)prow * 128 + pm]);
  float uu2 = __builtin_nontemporal_load(&u2[(size_t)prow * 128 + pm]);
  int h0g = w * 16;
  float bov = bo[h0g + lr];
  const s16x8* vtp = (const s16x8*)(VTbf + (size_t)(b * 256 + h0g + lr) * 128);
  s16x8 fv0 = vtp[lc], fv1 = vtp[4 + lc], fv2 = vtp[8 + lc], fv3 = vtp[12 + lc];

  // ---- phase L: logits MFMA. wave w: m-tile = w&7, k-half = w>>3 ----
  {
    int mt = w & 7, kh = w >> 3;
    const s16x8* ap = (const s16x8*)(Qbf + (size_t)(b * 128 + rtile + lr) * 256 + kh * 128);
    const s16x8* bp = (const s16x8*)(Kbf + (size_t)(b * 128 + mt * 16 + lr) * 256 + kh * 128);
    f32x4 acc = {0.f, 0.f, 0.f, 0.f};
#pragma unroll
    for (int kk = 0; kk < 4; kk++)
      acc = MFMA(ap[kk * 4 + lc], bp[kk * 4 + lc], acc);
    if ((lc >> 1) == (soff >> 3)) {
#pragma unroll
      for (int q = 0; q < 4; q++) Spp[kh][(4 * lc + q) & 7][mt * 16 + lr] = acc[q];
    }
    if (t < 544) ((unsigned int*)(Wb + (soff ^ 8) * 136))[t] = 0u;
  }
  __syncthreads();

  // ---- phase S: gumbel-sigmoid mask + scores + softmax ----
  {
    int half = (t >> 6) & 1;
    float lg = (Spp[0][prl][pm] + Spp[1][prl][pm]) * 0.0625f;
    float g1 = -__logf(-__logf(uu1 + 1e-20f) + 1e-20f);
    float g2 = -__logf(-__logf(uu2 + 1e-20f) + 1e-20f);
    float mkv = 1.0f / (1.0f + __expf(-(lg + g1 - g2)));   // TAU = 1
    __builtin_nontemporal_store(mkv, &o_mask[(size_t)prow * 128 + pm]);
    float sc = lg + __logf(mkv + 1e-8f);
    float v = sc;
#pragma unroll
    for (int off = 32; off >= 1; off >>= 1) v = fmaxf(v, __shfl_xor(v, off));
    if (l == 0) redmax[prl][half] = v;
    __syncthreads();
    float rmax = fmaxf(redmax[prl][0], redmax[prl][1]);
    float e = __expf(sc - rmax);
    float s = e;
#pragma unroll
    for (int off = 32; off >= 1; off >>= 1) s += __shfl_xor(s, off);
    if (l == 0) redsum[prl][half] = s;
    __syncthreads();
    float rsum = redsum[prl][0] + redsum[prl][1];
    float attn = e / rsum;
    __builtin_nontemporal_store(attn, &o_attn[(size_t)prow * 128 + pm]);
    Wb[(soff + prl) * 136 + pm] = f2bf(attn * mkv);
  }
  __syncthreads();

  // ---- phase PV: info = W x V. wave w -> h-tile h0g (4 MFMAs, prefetched B) --
  {
    s16x8 a0 = *(const s16x8*)(Wb + lr * 136 + 0 * 32 + lc * 8);
    s16x8 a1 = *(const s16x8*)(Wb + lr * 136 + 1 * 32 + lc * 8);
    s16x8 a2 = *(const s16x8*)(Wb + lr * 136 + 2 * 32 + lc * 8);
    s16x8 a3 = *(const s16x8*)(Wb + lr * 136 + 3 * 32 + lc * 8);
    f32x4 acc = {0.f, 0.f, 0.f, 0.f};
    acc = MFMA(a0, fv0, acc);
    acc = MFMA(a1, fv1, acc);
    acc = MFMA(a2, fv2, acc);
    acc = MFMA(a3, fv3, acc);
#pragma unroll
    for (int q = 0; q < 4; q++) Ib[(4 * lc + q) * 264 + h0g + lr] = f2bf(acc[q]);
  }
  __syncthreads();

  // ---- phase O: out = info x Wo^T. wave w -> g-tile g0 (8 MFMAs) ----
  {
    int g0 = w * 16;
    f32x4 acc = {0.f, 0.f, 0.f, 0.f};
#pragma unroll
    for (int kk = 0; kk < 8; kk++) {
      s16x8 a = *(const s16x8*)(Ib + lr * 264 + kk * 32 + lc * 8);
      s16x8 bfr = *(const s16x8*)(Wobf + (size_t)(g0 + lr) * 256 + kk * 32 + lc * 8);
      acc = MFMA(a, bfr, acc);
    }
    if ((lc >> 1) == (soff >> 3)) {
#pragma unroll
      for (int q = 0; q < 4; q++) {
        int rloc = (4 * lc + q) & 7;
        float val = acc[q] + bov;
        __builtin_nontemporal_store(val, &o_out[(size_t)(b * 128 + n0 + rloc) * 256 + g0 + lr]);
        outb[rloc * 260 + g0 + lr] = val;
      }
    }
  }
  __syncthreads();

  // ---- phase K: skill logits, all inputs from LDS. t = (rloc<<7)|(s<<3)|p ---
  {
    int rloc = t >> 7, s = (t >> 3) & 15, p = t & 7;
    int row = b * 128 + n0 + rloc;
    const float* wsr = &Wsb[s * 384];
    float acc = 0.f;
#pragma unroll
    for (int i = 0; i < 12; i++) {
      int cc = p * 48 + i * 4;
      float4 c4;
      if (cc < 128) c4 = *(const float4*)&cgb[rloc * 128 + cc];
      else          c4 = *(const float4*)&outb[rloc * 260 + (cc - 128)];
      float4 w4 = *(const float4*)&wsr[cc];
      acc = fmaf(w4.x, c4.x, fmaf(w4.y, c4.y, fmaf(w4.z, c4.z, fmaf(w4.w, c4.w, acc))));
    }
    acc += __shfl_xor(acc, 1);
    acc += __shfl_xor(acc, 2);
    acc += __shfl_xor(acc, 4);
    if (p == 0) __builtin_nontemporal_store(acc + bs[s], &o_logit[row * 16 + s]);
  }
}

extern "C" void kernel_launch(void* const* d_in, const int* in_sizes, int n_in,
                              void* d_out, int out_size, void* d_ws, size_t ws_size,
                              hipStream_t stream) {
  const float* goals        = (const float*)d_in[0];
  const float* agents       = (const float*)d_in[1];
  const float* agents_local = (const float*)d_in[2];
  const float* u1           = (const float*)d_in[3];
  const float* u2           = (const float*)d_in[4];
  const float* Wq = (const float*)d_in[5];
  const float* bq = (const float*)d_in[6];
  const float* Wk = (const float*)d_in[7];
  const float* bk = (const float*)d_in[8];
  const float* Wv = (const float*)d_in[9];
  const float* bv = (const float*)d_in[10];
  const float* Wo = (const float*)d_in[11];
  const float* bo = (const float*)d_in[12];
  const float* Wsm = (const float*)d_in[13];
  const float* bs  = (const float*)d_in[14];
  float* out = (float*)d_out;
  float* ws  = (float*)d_ws;

  proj_k<<<256, 512, 0, stream>>>(goals, agents, Wq, bq, Wk, bk, Wv, bv, Wo, ws);
  attn_k<<<256, 1024, 0, stream>>>(goals, agents_local, u1, u2, bo, Wsm, bs, ws, out);
}

// Round 20
// 27.475 us; speedup vs baseline: 1.4852x; 1.0167x over previous
//
#include <hip/hip_runtime.h>
#include <math.h>

// Problem constants: B=16, N=128, h=256, goal_dim=64, obs_dim=128, local=64, skills=16
// R20 = R19 (27.93us) + register-prefetch of phase-O's 8 Wobf fragments at
// kernel start (+32 VGPR, fits <128) + hoisted bs[] scalar. Same mechanism as
// R19's win: no load may sit un-overlapped after a barrier.

typedef float f32x4 __attribute__((ext_vector_type(4)));
typedef short s16x8 __attribute__((ext_vector_type(8)));

// ---- workspace layout (float offsets) ----
#define WOBF_OFF  0        // bf16 [256][256] (row-major, = original Wo layout)
#define QBF_OFF   32768    // bf16 [2048][256] row-major
#define KBF_OFF   294912   // bf16 [2048][256] row-major
#define VTBF_OFF  557056   // bf16 [16][256][128]  (V transposed per batch)

// ---- output layout (float offsets, tuple return order) ----
#define LOGIT_OFF 0        // [16][128][16]
#define MASK_OFF  32768    // [16][128][128]
#define ATTN_OFF  294912   // [16][128][128]
#define OUT_OFF   557056   // [16][128][256]

static __device__ __forceinline__ unsigned short f2bf(float x) {
  unsigned int u = __float_as_uint(x);
  u = (u + 0x7fffu + ((u >> 16) & 1u)) >> 16;   // RNE
  return (unsigned short)u;
}
static __device__ __forceinline__ float bf2f(unsigned short h) {
  return __uint_as_float(((unsigned int)h) << 16);
}

// split 8 consecutive f32 (16B-aligned) into hi/lo bf16 MFMA fragments
static __device__ __forceinline__ void split8(const float* __restrict__ p,
                                              s16x8* hi, s16x8* lo) {
  float4 x0 = *(const float4*)p;
  float4 x1 = *(const float4*)(p + 4);
  float xs[8] = {x0.x, x0.y, x0.z, x0.w, x1.x, x1.y, x1.z, x1.w};
#pragma unroll
  for (int j = 0; j < 8; j++) {
    unsigned short h = f2bf(xs[j]);
    (*hi)[j] = (short)h;
    (*lo)[j] = (short)f2bf(xs[j] - bf2f(h));
  }
}
#define MFMA(a, b, c) __builtin_amdgcn_mfma_f32_16x16x32_bf16((a), (b), (c), 0, 0, 0)

// ---------------- proj_k: R10/R16 verbatim (XCD-aligned mapping) -------------
__global__ __launch_bounds__(512) void proj_k(
    const float* __restrict__ goals, const float* __restrict__ agents,
    const float* __restrict__ Wq, const float* __restrict__ bq,
    const float* __restrict__ Wk, const float* __restrict__ bk,
    const float* __restrict__ Wv, const float* __restrict__ bv,
    const float* __restrict__ Wo, float* __restrict__ ws) {
  unsigned short* qbf  = (unsigned short*)(ws + QBF_OFF);
  unsigned short* kbf  = (unsigned short*)(ws + KBF_OFF);
  unsigned short* vtbf = (unsigned short*)(ws + VTBF_OFF);
  unsigned short* wobf = (unsigned short*)(ws + WOBF_OFF);

  __shared__ __align__(16) float xg[16 * 68];
  __shared__ __align__(16) float xa[16 * 132];

  int t = threadIdx.x;
  int bid = blockIdx.x;
  int xcd = bid & 7, j = bid >> 3;
  int bb = 2 * xcd + (j & 1);
  int sub = j >> 1;
  int r0 = bb * 128 + (sub >> 1) * 16;
  int colbase = (sub & 1) * 128;

  for (int i = t; i < 1024; i += 512) xg[(i >> 6) * 68 + (i & 63)] = goals[(size_t)r0 * 64 + i];
  for (int i = t; i < 2048; i += 512) xa[(i >> 7) * 132 + (i & 127)] = agents[(size_t)r0 * 128 + i];
  if (t < 256) {
    int jj = bid * 256 + t;
    wobf[jj] = f2bf(Wo[jj]);
  }
  __syncthreads();

  int w = t >> 6, l = t & 63, lr = l & 15, lc = l >> 4;
  int oc = colbase + w * 16 + lr;

  {
    f32x4 acc = {0.f, 0.f, 0.f, 0.f};
#pragma unroll
    for (int kk = 0; kk < 2; kk++) {
      s16x8 ahi, alo, bhi, blo;
      split8(&xg[lr * 68 + kk * 32 + lc * 8], &ahi, &alo);
      split8(&Wq[(size_t)oc * 64 + kk * 32 + lc * 8], &bhi, &blo);
      acc = MFMA(ahi, bhi, acc);
      acc = MFMA(alo, bhi, acc);
      acc = MFMA(ahi, blo, acc);
    }
    float bqv = bq[oc];
#pragma unroll
    for (int q = 0; q < 4; q++)
      qbf[(size_t)(r0 + 4 * lc + q) * 256 + oc] = f2bf(acc[q] + bqv);
  }
  {
    f32x4 acc = {0.f, 0.f, 0.f, 0.f};
#pragma unroll
    for (int kk = 0; kk < 4; kk++) {
      s16x8 ahi, alo, bhi, blo;
      split8(&xa[lr * 132 + kk * 32 + lc * 8], &ahi, &alo);
      split8(&Wk[(size_t)oc * 128 + kk * 32 + lc * 8], &bhi, &blo);
      acc = MFMA(ahi, bhi, acc);
      acc = MFMA(alo, bhi, acc);
      acc = MFMA(ahi, blo, acc);
    }
    float bkv = bk[oc];
#pragma unroll
    for (int q = 0; q < 4; q++)
      kbf[(size_t)(r0 + 4 * lc + q) * 256 + oc] = f2bf(acc[q] + bkv);
  }
  {
    f32x4 acc = {0.f, 0.f, 0.f, 0.f};
#pragma unroll
    for (int kk = 0; kk < 4; kk++) {
      s16x8 ahi, alo, bhi, blo;
      split8(&xa[lr * 132 + kk * 32 + lc * 8], &ahi, &alo);
      split8(&Wv[(size_t)oc * 128 + kk * 32 + lc * 8], &bhi, &blo);
      acc = MFMA(ahi, bhi, acc);
      acc = MFMA(alo, bhi, acc);
      acc = MFMA(ahi, blo, acc);
    }
    float bvv = bv[oc];
    int m0 = r0 & 127;
#pragma unroll
    for (int q = 0; q < 4; q++)
      vtbf[(size_t)(bb * 256 + oc) * 128 + m0 + 4 * lc + q] = f2bf(acc[q] + bvv);
  }
}

// ---------------- attn_k: R19 + Wobf register prefetch + bs hoist ------------
__global__ __launch_bounds__(1024) void attn_k(
    const float* __restrict__ goals, const float* __restrict__ agents_local,
    const float* __restrict__ u1, const float* __restrict__ u2,
    const float* __restrict__ bo, const float* __restrict__ Wsm,
    const float* __restrict__ bs, const float* __restrict__ ws,
    float* __restrict__ out) {
  const unsigned short* Qbf  = (const unsigned short*)(ws + QBF_OFF);
  const unsigned short* Kbf  = (const unsigned short*)(ws + KBF_OFF);
  const unsigned short* VTbf = (const unsigned short*)(ws + VTBF_OFF);
  const unsigned short* Wobf = (const unsigned short*)(ws + WOBF_OFF);
  float* o_logit = out + LOGIT_OFF;
  float* o_mask  = out + MASK_OFF;
  float* o_attn  = out + ATTN_OFF;
  float* o_out   = out + OUT_OFF;

  int bid = blockIdx.x;
  int xcd = bid & 7, idx = bid >> 3;
  int b  = 2 * xcd + (idx & 1);
  int n0 = (idx >> 1) << 3;
  int rtile = n0 & 0x70;
  int soff  = n0 & 8;
  int t = threadIdx.x;
  int w = t >> 6, l = t & 63, lr = l & 15, lc = l >> 4;

  __shared__ __align__(16) float Spp[2][8][132];
  __shared__ __align__(16) unsigned short Wb[16 * 136];
  __shared__ __align__(16) unsigned short Ib[16 * 264];
  __shared__ __align__(16) float outb[8 * 260];
  __shared__ __align__(16) float Wsb[16 * 384];   // Wsm staged (24 KB)
  __shared__ __align__(16) float cgb[8 * 128];    // agents_local||goals rows (4 KB)
  __shared__ float redmax[8][2], redsum[8][2];

  // ---- SK-input staging (issued FIRST: latency hides under phases L..O) ----
#pragma unroll
  for (int i = 0; i < 6; i++) Wsb[t + i * 1024] = Wsm[t + i * 1024];
  {
    int r = t >> 7, c = t & 127;
    int row = b * 128 + n0 + r;
    cgb[r * 128 + c] = (c < 64) ? agents_local[(size_t)row * 64 + c]
                                : goals[(size_t)row * 64 + (c - 64)];
  }

  // ---- prefetch: u1/u2 (NT), bo, bs, 4 VT frags, 8 Wobf frags ----
  int pm = t & 127, prl = t >> 7;
  int prow = b * 128 + n0 + prl;
  float uu1 = __builtin_nontemporal_load(&u1[(size_t)prow * 128 + pm]);
  float uu2 = __builtin_nontemporal_load(&u2[(size_t)prow * 128 + pm]);
  int h0g = w * 16;
  float bov = bo[h0g + lr];
  float bsv = bs[(t >> 3) & 15];
  const s16x8* vtp = (const s16x8*)(VTbf + (size_t)(b * 256 + h0g + lr) * 128);
  s16x8 fv0 = vtp[lc], fv1 = vtp[4 + lc], fv2 = vtp[8 + lc], fv3 = vtp[12 + lc];
  const s16x8* wop = (const s16x8*)(Wobf + (size_t)(h0g + lr) * 256);
  s16x8 fo0 = wop[lc],      fo1 = wop[4 + lc],  fo2 = wop[8 + lc],  fo3 = wop[12 + lc];
  s16x8 fo4 = wop[16 + lc], fo5 = wop[20 + lc], fo6 = wop[24 + lc], fo7 = wop[28 + lc];

  // ---- phase L: logits MFMA. wave w: m-tile = w&7, k-half = w>>3 ----
  {
    int mt = w & 7, kh = w >> 3;
    const s16x8* ap = (const s16x8*)(Qbf + (size_t)(b * 128 + rtile + lr) * 256 + kh * 128);
    const s16x8* bp = (const s16x8*)(Kbf + (size_t)(b * 128 + mt * 16 + lr) * 256 + kh * 128);
    f32x4 acc = {0.f, 0.f, 0.f, 0.f};
#pragma unroll
    for (int kk = 0; kk < 4; kk++)
      acc = MFMA(ap[kk * 4 + lc], bp[kk * 4 + lc], acc);
    if ((lc >> 1) == (soff >> 3)) {
#pragma unroll
      for (int q = 0; q < 4; q++) Spp[kh][(4 * lc + q) & 7][mt * 16 + lr] = acc[q];
    }
    if (t < 544) ((unsigned int*)(Wb + (soff ^ 8) * 136))[t] = 0u;
  }
  __syncthreads();

  // ---- phase S: gumbel-sigmoid mask + scores + softmax ----
  {
    int half = (t >> 6) & 1;
    float lg = (Spp[0][prl][pm] + Spp[1][prl][pm]) * 0.0625f;
    float g1 = -__logf(-__logf(uu1 + 1e-20f) + 1e-20f);
    float g2 = -__logf(-__logf(uu2 + 1e-20f) + 1e-20f);
    float mkv = 1.0f / (1.0f + __expf(-(lg + g1 - g2)));   // TAU = 1
    __builtin_nontemporal_store(mkv, &o_mask[(size_t)prow * 128 + pm]);
    float sc = lg + __logf(mkv + 1e-8f);
    float v = sc;
#pragma unroll
    for (int off = 32; off >= 1; off >>= 1) v = fmaxf(v, __shfl_xor(v, off));
    if (l == 0) redmax[prl][half] = v;
    __syncthreads();
    float rmax = fmaxf(redmax[prl][0], redmax[prl][1]);
    float e = __expf(sc - rmax);
    float s = e;
#pragma unroll
    for (int off = 32; off >= 1; off >>= 1) s += __shfl_xor(s, off);
    if (l == 0) redsum[prl][half] = s;
    __syncthreads();
    float rsum = redsum[prl][0] + redsum[prl][1];
    float attn = e / rsum;
    __builtin_nontemporal_store(attn, &o_attn[(size_t)prow * 128 + pm]);
    Wb[(soff + prl) * 136 + pm] = f2bf(attn * mkv);
  }
  __syncthreads();

  // ---- phase PV: info = W x V. wave w -> h-tile h0g (4 MFMAs, prefetched B) --
  {
    s16x8 a0 = *(const s16x8*)(Wb + lr * 136 + 0 * 32 + lc * 8);
    s16x8 a1 = *(const s16x8*)(Wb + lr * 136 + 1 * 32 + lc * 8);
    s16x8 a2 = *(const s16x8*)(Wb + lr * 136 + 2 * 32 + lc * 8);
    s16x8 a3 = *(const s16x8*)(Wb + lr * 136 + 3 * 32 + lc * 8);
    f32x4 acc = {0.f, 0.f, 0.f, 0.f};
    acc = MFMA(a0, fv0, acc);
    acc = MFMA(a1, fv1, acc);
    acc = MFMA(a2, fv2, acc);
    acc = MFMA(a3, fv3, acc);
#pragma unroll
    for (int q = 0; q < 4; q++) Ib[(4 * lc + q) * 264 + h0g + lr] = f2bf(acc[q]);
  }
  __syncthreads();

  // ---- phase O: out = info x Wo^T. wave w -> g-tile (8 MFMAs, prefetched B) --
  {
    f32x4 acc = {0.f, 0.f, 0.f, 0.f};
    acc = MFMA(*(const s16x8*)(Ib + lr * 264 + 0 * 32 + lc * 8), fo0, acc);
    acc = MFMA(*(const s16x8*)(Ib + lr * 264 + 1 * 32 + lc * 8), fo1, acc);
    acc = MFMA(*(const s16x8*)(Ib + lr * 264 + 2 * 32 + lc * 8), fo2, acc);
    acc = MFMA(*(const s16x8*)(Ib + lr * 264 + 3 * 32 + lc * 8), fo3, acc);
    acc = MFMA(*(const s16x8*)(Ib + lr * 264 + 4 * 32 + lc * 8), fo4, acc);
    acc = MFMA(*(const s16x8*)(Ib + lr * 264 + 5 * 32 + lc * 8), fo5, acc);
    acc = MFMA(*(const s16x8*)(Ib + lr * 264 + 6 * 32 + lc * 8), fo6, acc);
    acc = MFMA(*(const s16x8*)(Ib + lr * 264 + 7 * 32 + lc * 8), fo7, acc);
    if ((lc >> 1) == (soff >> 3)) {
#pragma unroll
      for (int q = 0; q < 4; q++) {
        int rloc = (4 * lc + q) & 7;
        float val = acc[q] + bov;
        __builtin_nontemporal_store(val, &o_out[(size_t)(b * 128 + n0 + rloc) * 256 + h0g + lr]);
        outb[rloc * 260 + h0g + lr] = val;
      }
    }
  }
  __syncthreads();

  // ---- phase K: skill logits, all inputs from LDS. t = (rloc<<7)|(s<<3)|p ---
  {
    int rloc = t >> 7, s = (t >> 3) & 15, p = t & 7;
    int row = b * 128 + n0 + rloc;
    const float* wsr = &Wsb[s * 384];
    float acc = 0.f;
#pragma unroll
    for (int i = 0; i < 12; i++) {
      int cc = p * 48 + i * 4;
      float4 c4;
      if (cc < 128) c4 = *(const float4*)&cgb[rloc * 128 + cc];
      else          c4 = *(const float4*)&outb[rloc * 260 + (cc - 128)];
      float4 w4 = *(const float4*)&wsr[cc];
      acc = fmaf(w4.x, c4.x, fmaf(w4.y, c4.y, fmaf(w4.z, c4.z, fmaf(w4.w, c4.w, acc))));
    }
    acc += __shfl_xor(acc, 1);
    acc += __shfl_xor(acc, 2);
    acc += __shfl_xor(acc, 4);
    if (p == 0) __builtin_nontemporal_store(acc + bsv, &o_logit[row * 16 + s]);
  }
}

extern "C" void kernel_launch(void* const* d_in, const int* in_sizes, int n_in,
                              void* d_out, int out_size, void* d_ws, size_t ws_size,
                              hipStream_t stream) {
  const float* goals        = (const float*)d_in[0];
  const float* agents       = (const float*)d_in[1];
  const float* agents_local = (const float*)d_in[2];
  const float* u1           = (const float*)d_in[3];
  const float* u2           = (const float*)d_in[4];
  const float* Wq = (const float*)d_in[5];
  const float* bq = (const float*)d_in[6];
  const float* Wk = (const float*)d_in[7];
  const float* bk = (const float*)d_in[8];
  const float* Wv = (const float*)d_in[9];
  const float* bv = (const float*)d_in[10];
  const float* Wo = (const float*)d_in[11];
  const float* bo = (const float*)d_in[12];
  const float* Wsm = (const float*)d_in[13];
  const float* bs  = (const float*)d_in[14];
  float* out = (float*)d_out;
  float* ws  = (float*)d_ws;

  proj_k<<<256, 512, 0, stream>>>(goals, agents, Wq, bq, Wk, bk, Wv, bv, Wo, ws);
  attn_k<<<256, 1024, 0, stream>>>(goals, agents_local, u1, u2, bo, Wsm, bs, ws, out);
}

// Round 21
// 27.198 us; speedup vs baseline: 1.5003x; 1.0102x over previous
//
#include <hip/hip_runtime.h>
#include <math.h>

// Problem constants: B=16, N=128, h=256, goal_dim=64, obs_dim=128, local=64, skills=16
// R21 = R20 (27.47us) + (a) phase-S softmax reworked to one-row-per-wave
// (pure shfl reductions, 2 block barriers removed, 6 -> 4 barriers) and
// (b) proj_k K/V phases share the A-operand hi/lo splits (computed once).

typedef float f32x4 __attribute__((ext_vector_type(4)));
typedef short s16x8 __attribute__((ext_vector_type(8)));

// ---- workspace layout (float offsets) ----
#define WOBF_OFF  0        // bf16 [256][256] (row-major, = original Wo layout)
#define QBF_OFF   32768    // bf16 [2048][256] row-major
#define KBF_OFF   294912   // bf16 [2048][256] row-major
#define VTBF_OFF  557056   // bf16 [16][256][128]  (V transposed per batch)

// ---- output layout (float offsets, tuple return order) ----
#define LOGIT_OFF 0        // [16][128][16]
#define MASK_OFF  32768    // [16][128][128]
#define ATTN_OFF  294912   // [16][128][128]
#define OUT_OFF   557056   // [16][128][256]

static __device__ __forceinline__ unsigned short f2bf(float x) {
  unsigned int u = __float_as_uint(x);
  u = (u + 0x7fffu + ((u >> 16) & 1u)) >> 16;   // RNE
  return (unsigned short)u;
}
static __device__ __forceinline__ float bf2f(unsigned short h) {
  return __uint_as_float(((unsigned int)h) << 16);
}

// split 8 consecutive f32 (16B-aligned) into hi/lo bf16 MFMA fragments
static __device__ __forceinline__ void split8(const float* __restrict__ p,
                                              s16x8* hi, s16x8* lo) {
  float4 x0 = *(const float4*)p;
  float4 x1 = *(const float4*)(p + 4);
  float xs[8] = {x0.x, x0.y, x0.z, x0.w, x1.x, x1.y, x1.z, x1.w};
#pragma unroll
  for (int j = 0; j < 8; j++) {
    unsigned short h = f2bf(xs[j]);
    (*hi)[j] = (short)h;
    (*lo)[j] = (short)f2bf(xs[j] - bf2f(h));
  }
}
#define MFMA(a, b, c) __builtin_amdgcn_mfma_f32_16x16x32_bf16((a), (b), (c), 0, 0, 0)

// ---------------- proj_k: R16 + shared K/V A-splits ----------------
__global__ __launch_bounds__(512) void proj_k(
    const float* __restrict__ goals, const float* __restrict__ agents,
    const float* __restrict__ Wq, const float* __restrict__ bq,
    const float* __restrict__ Wk, const float* __restrict__ bk,
    const float* __restrict__ Wv, const float* __restrict__ bv,
    const float* __restrict__ Wo, float* __restrict__ ws) {
  unsigned short* qbf  = (unsigned short*)(ws + QBF_OFF);
  unsigned short* kbf  = (unsigned short*)(ws + KBF_OFF);
  unsigned short* vtbf = (unsigned short*)(ws + VTBF_OFF);
  unsigned short* wobf = (unsigned short*)(ws + WOBF_OFF);

  __shared__ __align__(16) float xg[16 * 68];
  __shared__ __align__(16) float xa[16 * 132];

  int t = threadIdx.x;
  int bid = blockIdx.x;
  int xcd = bid & 7, j = bid >> 3;
  int bb = 2 * xcd + (j & 1);
  int sub = j >> 1;
  int r0 = bb * 128 + (sub >> 1) * 16;
  int colbase = (sub & 1) * 128;

  for (int i = t; i < 1024; i += 512) xg[(i >> 6) * 68 + (i & 63)] = goals[(size_t)r0 * 64 + i];
  for (int i = t; i < 2048; i += 512) xa[(i >> 7) * 132 + (i & 127)] = agents[(size_t)r0 * 128 + i];
  if (t < 256) {
    int jj = bid * 256 + t;
    wobf[jj] = f2bf(Wo[jj]);
  }
  __syncthreads();

  int w = t >> 6, l = t & 63, lr = l & 15, lc = l >> 4;
  int oc = colbase + w * 16 + lr;

  // ---- Q: k=64, hi/lo ----
  {
    f32x4 acc = {0.f, 0.f, 0.f, 0.f};
#pragma unroll
    for (int kk = 0; kk < 2; kk++) {
      s16x8 ahi, alo, bhi, blo;
      split8(&xg[lr * 68 + kk * 32 + lc * 8], &ahi, &alo);
      split8(&Wq[(size_t)oc * 64 + kk * 32 + lc * 8], &bhi, &blo);
      acc = MFMA(ahi, bhi, acc);
      acc = MFMA(alo, bhi, acc);
      acc = MFMA(ahi, blo, acc);
    }
    float bqv = bq[oc];
#pragma unroll
    for (int q = 0; q < 4; q++)
      qbf[(size_t)(r0 + 4 * lc + q) * 256 + oc] = f2bf(acc[q] + bqv);
  }
  // ---- K + V fused: A-splits computed once, reused for both ----
  {
    f32x4 accK = {0.f, 0.f, 0.f, 0.f};
    f32x4 accV = {0.f, 0.f, 0.f, 0.f};
#pragma unroll
    for (int kk = 0; kk < 4; kk++) {
      s16x8 ahi, alo;
      split8(&xa[lr * 132 + kk * 32 + lc * 8], &ahi, &alo);
      s16x8 bhiK, bloK, bhiV, bloV;
      split8(&Wk[(size_t)oc * 128 + kk * 32 + lc * 8], &bhiK, &bloK);
      split8(&Wv[(size_t)oc * 128 + kk * 32 + lc * 8], &bhiV, &bloV);
      accK = MFMA(ahi, bhiK, accK);
      accK = MFMA(alo, bhiK, accK);
      accK = MFMA(ahi, bloK, accK);
      accV = MFMA(ahi, bhiV, accV);
      accV = MFMA(alo, bhiV, accV);
      accV = MFMA(ahi, bloV, accV);
    }
    float bkv = bk[oc], bvv = bv[oc];
    int m0 = r0 & 127;
#pragma unroll
    for (int q = 0; q < 4; q++) {
      kbf[(size_t)(r0 + 4 * lc + q) * 256 + oc] = f2bf(accK[q] + bkv);
      vtbf[(size_t)(bb * 256 + oc) * 128 + m0 + 4 * lc + q] = f2bf(accV[q] + bvv);
    }
  }
}

// ---------------- attn_k: R20 + barrier-free phase S (row-per-wave) ----------
__global__ __launch_bounds__(1024) void attn_k(
    const float* __restrict__ goals, const float* __restrict__ agents_local,
    const float* __restrict__ u1, const float* __restrict__ u2,
    const float* __restrict__ bo, const float* __restrict__ Wsm,
    const float* __restrict__ bs, const float* __restrict__ ws,
    float* __restrict__ out) {
  const unsigned short* Qbf  = (const unsigned short*)(ws + QBF_OFF);
  const unsigned short* Kbf  = (const unsigned short*)(ws + KBF_OFF);
  const unsigned short* VTbf = (const unsigned short*)(ws + VTBF_OFF);
  const unsigned short* Wobf = (const unsigned short*)(ws + WOBF_OFF);
  float* o_logit = out + LOGIT_OFF;
  float* o_mask  = out + MASK_OFF;
  float* o_attn  = out + ATTN_OFF;
  float* o_out   = out + OUT_OFF;

  int bid = blockIdx.x;
  int xcd = bid & 7, idx = bid >> 3;
  int b  = 2 * xcd + (idx & 1);
  int n0 = (idx >> 1) << 3;
  int rtile = n0 & 0x70;
  int soff  = n0 & 8;
  int t = threadIdx.x;
  int w = t >> 6, l = t & 63, lr = l & 15, lc = l >> 4;

  __shared__ __align__(16) float Spp[2][8][132];
  __shared__ __align__(16) unsigned short Wb[16 * 136];
  __shared__ __align__(16) unsigned short Ib[16 * 264];
  __shared__ __align__(16) float outb[8 * 260];
  __shared__ __align__(16) float Wsb[16 * 384];   // Wsm staged (24 KB)
  __shared__ __align__(16) float cgb[8 * 128];    // agents_local||goals rows (4 KB)

  // ---- SK-input staging (issued FIRST: latency hides under phases L..O) ----
#pragma unroll
  for (int i = 0; i < 6; i++) Wsb[t + i * 1024] = Wsm[t + i * 1024];
  {
    int r = t >> 7, c = t & 127;
    int row = b * 128 + n0 + r;
    cgb[r * 128 + c] = (c < 64) ? agents_local[(size_t)row * 64 + c]
                                : goals[(size_t)row * 64 + (c - 64)];
  }

  // ---- prefetch: u1/u2 (float2, waves 0-7), bo, bs, VT + Wobf frags ----
  float2 uu1v = make_float2(0.f, 0.f), uu2v = make_float2(0.f, 0.f);
  if (w < 8) {
    int srow = b * 128 + n0 + w;
    uu1v = *(const float2*)&u1[(size_t)srow * 128 + 2 * l];
    uu2v = *(const float2*)&u2[(size_t)srow * 128 + 2 * l];
  }
  int h0g = w * 16;
  float bov = bo[h0g + lr];
  float bsv = bs[(t >> 3) & 15];
  const s16x8* vtp = (const s16x8*)(VTbf + (size_t)(b * 256 + h0g + lr) * 128);
  s16x8 fv0 = vtp[lc], fv1 = vtp[4 + lc], fv2 = vtp[8 + lc], fv3 = vtp[12 + lc];
  const s16x8* wop = (const s16x8*)(Wobf + (size_t)(h0g + lr) * 256);
  s16x8 fo0 = wop[lc],      fo1 = wop[4 + lc],  fo2 = wop[8 + lc],  fo3 = wop[12 + lc];
  s16x8 fo4 = wop[16 + lc], fo5 = wop[20 + lc], fo6 = wop[24 + lc], fo7 = wop[28 + lc];

  // ---- phase L: logits MFMA. wave w: m-tile = w&7, k-half = w>>3 ----
  {
    int mt = w & 7, kh = w >> 3;
    const s16x8* ap = (const s16x8*)(Qbf + (size_t)(b * 128 + rtile + lr) * 256 + kh * 128);
    const s16x8* bp = (const s16x8*)(Kbf + (size_t)(b * 128 + mt * 16 + lr) * 256 + kh * 128);
    f32x4 acc = {0.f, 0.f, 0.f, 0.f};
#pragma unroll
    for (int kk = 0; kk < 4; kk++)
      acc = MFMA(ap[kk * 4 + lc], bp[kk * 4 + lc], acc);
    if ((lc >> 1) == (soff >> 3)) {
#pragma unroll
      for (int q = 0; q < 4; q++) Spp[kh][(4 * lc + q) & 7][mt * 16 + lr] = acc[q];
    }
    if (t < 544) ((unsigned int*)(Wb + (soff ^ 8) * 136))[t] = 0u;
  }
  __syncthreads();

  // ---- phase S: softmax, one row per wave (waves 0-7), pure shfl, 0 barriers -
  if (w < 8) {
    int m0 = 2 * l;
    int row = b * 128 + n0 + w;
    float lg0 = (Spp[0][w][m0]     + Spp[1][w][m0])     * 0.0625f;
    float lg1 = (Spp[0][w][m0 + 1] + Spp[1][w][m0 + 1]) * 0.0625f;
    float g10 = -__logf(-__logf(uu1v.x + 1e-20f) + 1e-20f);
    float g20 = -__logf(-__logf(uu2v.x + 1e-20f) + 1e-20f);
    float g11 = -__logf(-__logf(uu1v.y + 1e-20f) + 1e-20f);
    float g21 = -__logf(-__logf(uu2v.y + 1e-20f) + 1e-20f);
    float mk0 = 1.0f / (1.0f + __expf(-(lg0 + g10 - g20)));   // TAU = 1
    float mk1 = 1.0f / (1.0f + __expf(-(lg1 + g11 - g21)));
    *(float2*)&o_mask[(size_t)row * 128 + m0] = make_float2(mk0, mk1);
    float sc0 = lg0 + __logf(mk0 + 1e-8f);
    float sc1 = lg1 + __logf(mk1 + 1e-8f);
    float v = fmaxf(sc0, sc1);
#pragma unroll
    for (int off = 32; off >= 1; off >>= 1) v = fmaxf(v, __shfl_xor(v, off));
    float e0 = __expf(sc0 - v), e1 = __expf(sc1 - v);
    float s = e0 + e1;
#pragma unroll
    for (int off = 32; off >= 1; off >>= 1) s += __shfl_xor(s, off);
    float at0 = e0 / s, at1 = e1 / s;
    *(float2*)&o_attn[(size_t)row * 128 + m0] = make_float2(at0, at1);
    Wb[(soff + w) * 136 + m0]     = f2bf(at0 * mk0);
    Wb[(soff + w) * 136 + m0 + 1] = f2bf(at1 * mk1);
  }
  __syncthreads();

  // ---- phase PV: info = W x V. wave w -> h-tile h0g (4 MFMAs, prefetched B) --
  {
    s16x8 a0 = *(const s16x8*)(Wb + lr * 136 + 0 * 32 + lc * 8);
    s16x8 a1 = *(const s16x8*)(Wb + lr * 136 + 1 * 32 + lc * 8);
    s16x8 a2 = *(const s16x8*)(Wb + lr * 136 + 2 * 32 + lc * 8);
    s16x8 a3 = *(const s16x8*)(Wb + lr * 136 + 3 * 32 + lc * 8);
    f32x4 acc = {0.f, 0.f, 0.f, 0.f};
    acc = MFMA(a0, fv0, acc);
    acc = MFMA(a1, fv1, acc);
    acc = MFMA(a2, fv2, acc);
    acc = MFMA(a3, fv3, acc);
#pragma unroll
    for (int q = 0; q < 4; q++) Ib[(4 * lc + q) * 264 + h0g + lr] = f2bf(acc[q]);
  }
  __syncthreads();

  // ---- phase O: out = info x Wo^T. wave w -> g-tile (8 MFMAs, prefetched B) --
  {
    f32x4 acc = {0.f, 0.f, 0.f, 0.f};
    acc = MFMA(*(const s16x8*)(Ib + lr * 264 + 0 * 32 + lc * 8), fo0, acc);
    acc = MFMA(*(const s16x8*)(Ib + lr * 264 + 1 * 32 + lc * 8), fo1, acc);
    acc = MFMA(*(const s16x8*)(Ib + lr * 264 + 2 * 32 + lc * 8), fo2, acc);
    acc = MFMA(*(const s16x8*)(Ib + lr * 264 + 3 * 32 + lc * 8), fo3, acc);
    acc = MFMA(*(const s16x8*)(Ib + lr * 264 + 4 * 32 + lc * 8), fo4, acc);
    acc = MFMA(*(const s16x8*)(Ib + lr * 264 + 5 * 32 + lc * 8), fo5, acc);
    acc = MFMA(*(const s16x8*)(Ib + lr * 264 + 6 * 32 + lc * 8), fo6, acc);
    acc = MFMA(*(const s16x8*)(Ib + lr * 264 + 7 * 32 + lc * 8), fo7, acc);
    if ((lc >> 1) == (soff >> 3)) {
#pragma unroll
      for (int q = 0; q < 4; q++) {
        int rloc = (4 * lc + q) & 7;
        float val = acc[q] + bov;
        __builtin_nontemporal_store(val, &o_out[(size_t)(b * 128 + n0 + rloc) * 256 + h0g + lr]);
        outb[rloc * 260 + h0g + lr] = val;
      }
    }
  }
  __syncthreads();

  // ---- phase K: skill logits, all inputs from LDS. t = (rloc<<7)|(s<<3)|p ---
  {
    int rloc = t >> 7, s = (t >> 3) & 15, p = t & 7;
    int row = b * 128 + n0 + rloc;
    const float* wsr = &Wsb[s * 384];
    float acc = 0.f;
#pragma unroll
    for (int i = 0; i < 12; i++) {
      int cc = p * 48 + i * 4;
      float4 c4;
      if (cc < 128) c4 = *(const float4*)&cgb[rloc * 128 + cc];
      else          c4 = *(const float4*)&outb[rloc * 260 + (cc - 128)];
      float4 w4 = *(const float4*)&wsr[cc];
      acc = fmaf(w4.x, c4.x, fmaf(w4.y, c4.y, fmaf(w4.z, c4.z, fmaf(w4.w, c4.w, acc))));
    }
    acc += __shfl_xor(acc, 1);
    acc += __shfl_xor(acc, 2);
    acc += __shfl_xor(acc, 4);
    if (p == 0) __builtin_nontemporal_store(acc + bsv, &o_logit[row * 16 + s]);
  }
}

extern "C" void kernel_launch(void* const* d_in, const int* in_sizes, int n_in,
                              void* d_out, int out_size, void* d_ws, size_t ws_size,
                              hipStream_t stream) {
  const float* goals        = (const float*)d_in[0];
  const float* agents       = (const float*)d_in[1];
  const float* agents_local = (const float*)d_in[2];
  const float* u1           = (const float*)d_in[3];
  const float* u2           = (const float*)d_in[4];
  const float* Wq = (const float*)d_in[5];
  const float* bq = (const float*)d_in[6];
  const float* Wk = (const float*)d_in[7];
  const float* bk = (const float*)d_in[8];
  const float* Wv = (const float*)d_in[9];
  const float* bv = (const float*)d_in[10];
  const float* Wo = (const float*)d_in[11];
  const float* bo = (const float*)d_in[12];
  const float* Wsm = (const float*)d_in[13];
  const float* bs  = (const float*)d_in[14];
  float* out = (float*)d_out;
  float* ws  = (float*)d_ws;

  proj_k<<<256, 512, 0, stream>>>(goals, agents, Wq, bq, Wk, bk, Wv, bv, Wo, ws);
  attn_k<<<256, 1024, 0, stream>>>(goals, agents_local, u1, u2, bo, Wsm, bs, ws, out);
}